// Round 18
// baseline (92.288 us; speedup 1.0000x reference)
//
#include <hip/hip_runtime.h>
#include <hip/hip_bf16.h>
#include <math.h>

#define S_LEN 2048
#define NHEAD 16
#define DHEAD 128

typedef __attribute__((ext_vector_type(8)))  _Float16 f16x8;
typedef __attribute__((ext_vector_type(4)))  _Float16 f16x4;
typedef __attribute__((ext_vector_type(4)))  float    f32x4;
typedef __attribute__((ext_vector_type(16))) float    f32x16;

// vdst.hi32lanes <-> vsrc.lo32lanes   (HW-verified by round-2 passing)
__device__ __forceinline__ void permswap(unsigned &a, unsigned &b) {
    asm volatile("v_permlane32_swap_b32 %0, %1" : "+v"(a), "+v"(b));
}

// async global->LDS, 16B per lane; LDS dest = wave-uniform base + lane*16
typedef __attribute__((address_space(3))) unsigned int lds_u32;
typedef __attribute__((address_space(1))) const unsigned int glb_u32;
__device__ __forceinline__ void gload16(const void* g, void* l) {
    __builtin_amdgcn_global_load_lds((glb_u32*)g, (lds_u32*)l, 16, 0, 0);
}

// ---------------------------------------------------------------------------
// Kernel 1: transpose the two SVD weight mats [H][d][e] f32 -> [H][e][d] f16
// ---------------------------------------------------------------------------
__global__ __launch_bounds__(256) void transpose_w_kernel(
    const float* __restrict__ w_qk, const float* __restrict__ w_v,
    _Float16* __restrict__ wqk_t, _Float16* __restrict__ wv_t)
{
    __shared__ float tile[32][33];
    const int mat = blockIdx.z;
    const int h   = blockIdx.y;
    const int t0  = blockIdx.x;
    const int dt  = (t0 >> 2) * 32;
    const int et  = (t0 & 3) * 32;
    const float* src = (mat ? w_v : w_qk) + (size_t)h * DHEAD * DHEAD;
    _Float16*   dst = (mat ? wv_t : wqk_t) + (size_t)h * DHEAD * DHEAD;
    const int tx = threadIdx.x & 31, ty = threadIdx.x >> 5;
#pragma unroll
    for (int k = 0; k < 4; ++k)
        tile[ty + 8 * k][tx] = src[(size_t)(dt + ty + 8 * k) * DHEAD + et + tx];
    __syncthreads();
#pragma unroll
    for (int k = 0; k < 4; ++k)
        dst[(size_t)(et + ty + 8 * k) * DHEAD + dt + tx] = (_Float16)tile[tx][ty + 8 * k];
}

// ---------------------------------------------------------------------------
// Kernel 2: per-head projection via MFMA 16x16x32 f16 (round-8-verified math).
// R18: output-column (cb) loop SPLIT across blockIdx.y (2-way) -> 4096 waves
// -> 4 waves/SIMD (was 2), halving latency exposure. Stores disjoint per y.
//   Qp[h][s][e] = (X_q[s] @ W_qk) * log2(e)/sqrt(128)  (f16; exp2 domain)
//   Kp[h][s][e] =  X_k[s] @ W_qk                       (f16)
//   Vt[h][e][s] =  X_v[s] @ W_v (plain transposed)     (f16)
// ---------------------------------------------------------------------------
__global__ __launch_bounds__(256) void proj_kernel(
    const float* __restrict__ q_in, const float* __restrict__ k_in,
    const float* __restrict__ v_in,
    const _Float16* __restrict__ wqk_t, const _Float16* __restrict__ wv_t,
    _Float16* __restrict__ Qp, _Float16* __restrict__ Kp, _Float16* __restrict__ Vt)
{
    const int h   = blockIdx.x >> 5;
    const int rb  = blockIdx.x & 31;
    const int cb0 = blockIdx.y * 4;          // this block's cb range [cb0, cb0+4)
    const int wv  = threadIdx.x >> 6;
    const int lane = threadIdx.x & 63;
    const int r16 = lane & 15;
    const int kg  = lane >> 4;
    const int s_base = rb * 64 + wv * 16;
    const int s_row  = s_base + r16;
    // 1/sqrt(128) * log2(e)  -- softmax runs in exp2 domain (R5/R10-verified)
    const float INV_NORM = 0.12752211758f;

    f16x8 aq[4], ak[4], av[4];
    {
        const float* qr = q_in + ((size_t)s_row * NHEAD + h) * DHEAD;
        const float* kr = k_in + ((size_t)s_row * NHEAD + h) * DHEAD;
        const float* vr = v_in + ((size_t)s_row * NHEAD + h) * DHEAD;
#pragma unroll
        for (int kb = 0; kb < 4; ++kb) {
            const int d0 = kb * 32 + kg * 8;
            const f32x4 q0 = *(const f32x4*)(qr + d0), q1 = *(const f32x4*)(qr + d0 + 4);
            const f32x4 k0 = *(const f32x4*)(kr + d0), k1 = *(const f32x4*)(kr + d0 + 4);
            const f32x4 v0 = *(const f32x4*)(vr + d0), v1 = *(const f32x4*)(vr + d0 + 4);
#pragma unroll
            for (int i = 0; i < 4; ++i) {
                aq[kb][i] = (_Float16)q0[i];  aq[kb][i + 4] = (_Float16)q1[i];
                ak[kb][i] = (_Float16)k0[i];  ak[kb][i + 4] = (_Float16)k1[i];
                av[kb][i] = (_Float16)v0[i];  av[kb][i + 4] = (_Float16)v1[i];
            }
        }
    }

    const _Float16* wq_h = wqk_t + (size_t)h * DHEAD * DHEAD;
    const _Float16* wv_h = wv_t  + (size_t)h * DHEAD * DHEAD;

#pragma unroll 2
    for (int cc = 0; cc < 4; ++cc) {
        const int cb = cb0 + cc;
        f32x4 accq = {0.f, 0.f, 0.f, 0.f};
        f32x4 acck = {0.f, 0.f, 0.f, 0.f};
        f32x4 accv = {0.f, 0.f, 0.f, 0.f};
        const int c = cb * 16 + r16;
#pragma unroll
        for (int kb = 0; kb < 4; ++kb) {
            const f16x8 bqk = *(const f16x8*)(wq_h + (size_t)c * DHEAD + kb * 32 + kg * 8);
            const f16x8 bv  = *(const f16x8*)(wv_h + (size_t)c * DHEAD + kb * 32 + kg * 8);
            // swapped: A = weight (rows = e), B = X (cols = s)
            accq = __builtin_amdgcn_mfma_f32_16x16x32_f16(bqk, aq[kb], accq, 0, 0, 0);
            acck = __builtin_amdgcn_mfma_f32_16x16x32_f16(bqk, ak[kb], acck, 0, 0, 0);
            accv = __builtin_amdgcn_mfma_f32_16x16x32_f16(av[kb], bv,  accv, 0, 0, 0);
        }
        // Q/K: D row = e = cb*16 + kg*4 + jj, col = s = s_base + r16
        f16x4 qv, kv4;
#pragma unroll
        for (int jj = 0; jj < 4; ++jj) {
            qv[jj]  = (_Float16)(accq[jj] * INV_NORM);
            kv4[jj] = (_Float16)acck[jj];
        }
        *(f16x4*)(Qp + ((size_t)h * S_LEN + s_base + r16) * DHEAD + cb * 16 + kg * 4) = qv;
        *(f16x4*)(Kp + ((size_t)h * S_LEN + s_base + r16) * DHEAD + cb * 16 + kg * 4) = kv4;
        // V: D row = s = s_base + kg*4 + jj, col = e = c  (plain transpose)
        f16x4 vvv;
#pragma unroll
        for (int jj = 0; jj < 4; ++jj) vvv[jj] = (_Float16)accv[jj];
        *(f16x4*)(Vt + ((size_t)h * DHEAD + c) * S_LEN + s_base + kg * 4) = vvv;
    }
}

// ---------------------------------------------------------------------------
// Kernel 3: causal flash attention — R17-verified (byte-identical):
// sequential-phase schedule + head-locality XCD swizzle (FETCH 97->12 MB).
// Grid (16, H); block 512 = 8 waves: role = w&3, qsub = w>>2.
// Phase 0: q-tile t = 31-x (heavy); phase 1: q-tile t = x (light).
// ---------------------------------------------------------------------------
__device__ __forceinline__ void stage_k4(const _Float16* kbase, char* kst,
                                         int w, int lane, int par, int inext,
                                         int jmax_lock) {
#pragma unroll
    for (int cidx = 0; cidx < 4; ++cidx) {
        const int c    = 4 * w + cidx;        // 32 chunks = 4 tiles of 8KB
        const int slot = c >> 3;              // tile slot 0..3 (= role)
        const int cc   = c & 7;               // 1KB chunk within tile
        const int jn   = 4 * inext + slot;
        if (jn < jmax_lock) {
            const int A    = cc * 1024 + lane * 16;          // linear tile offset
            const int srcO = A ^ (((A >> 8) & 15) << 4);     // inverse swizzle
            const char* g  = (const char*)kbase + (size_t)jn * 8192 + srcO;
            char*       l  = kst + (size_t)(slot * 2 + par) * 8192
                                 + cc * 1024;                // wave-uniform base
            gload16(g, l);
        }
    }
}

__global__ __launch_bounds__(512, 2) void attn_kernel(
    const _Float16* __restrict__ Qp, const _Float16* __restrict__ Kp,
    const _Float16* __restrict__ Vt, float* __restrict__ out)
{
    __shared__ _Float16 Kst[8][4096];        // [slot*2+parity] 32x128 f16 = 64 KB
    __shared__ _Float16 obuf[2][3][32][132]; // [qsub][role-1] partials ~50.7 KB
    __shared__ float    mlbuf[2][3][2][32];

    // --- head-locality XCD swizzle (T1): id = x + 16h round-robins XCDs by
    //     id&7; pick h' = id&7 (+8) so each XCD serves exactly 2 heads.
    const int id  = blockIdx.x + (blockIdx.y << 4);
    const int xb  = id >> 4;
    const int h   = (id & 7) + 8 * ((id >> 3) & 1);

    const int w    = threadIdx.x >> 6;
    const int lane = threadIdx.x & 63;
    const int q    = lane & 31;
    const int hi   = lane >> 5;

    const int role = w & 3;
    const int qsub = w >> 2;

    const _Float16* kbase = Kp + (size_t)h * S_LEN * DHEAD;
    const _Float16* vbase = Vt + (size_t)h * DHEAD * S_LEN;

    const int lqk = q * DHEAD + hi * 8;   // lane offset in row-major [s][d]
    const int lv  = q * S_LEN + hi * 8;   // lane offset in [e][s]
    const int swq = (q & 15) << 4;        // read-side swizzle for K LDS

    for (int ph = 0; ph < 2; ++ph) {
        const int t     = ph ? xb : (31 - xb);
        const int q0w   = t * 64 + qsub * 32;
        const int jmax  = 2 * t + 1 + qsub;
        const int jlock = 2 * t + 2;            // block-uniform staging bound
        const int I     = (jlock + 3) >> 2;     // lockstep iterations
        const int q_abs = q0w + q;

        // Q fragments (B-operand): lane holds Q[q][16m + hi*8 + i]
        const _Float16* qbase = Qp + ((size_t)h * S_LEN + q0w) * DHEAD;
        f16x8 qf[8];
#pragma unroll
        for (int m = 0; m < 8; ++m)
            qf[m] = *(const f16x8*)(qbase + lqk + m * 16);

        // O^T accumulators: acc[eb] -> e = eb*32 + (i&3)+8*(i>>2)+4*hi, col q
        f32x16 acc[4];
#pragma unroll
        for (int e = 0; e < 4; ++e)
#pragma unroll
            for (int i = 0; i < 16; ++i) acc[e][i] = 0.f;
        float m_run = -1e30f, l_run = 0.f;

        // prologue: stage K tiles {0..3} into parity 0
        stage_k4(kbase, (char*)Kst, w, lane, 0, 0, jlock);

        int p = 0;
        for (int it = 0; it < I; ++it, p ^= 1) {
            __syncthreads();   // vmcnt(0) drain: fills for 'it' visible

            const int j   = 4 * it + role;
            const bool act = (j < jmax);
            const int kv0 = j * 32;

            // --- V fragments FIRST (L2 latency hides under ds_read+QK+softmax)
            f16x8 vf[8];
            if (act) {
#pragma unroll
                for (int e = 0; e < 4; ++e) {
                    const _Float16* vp = vbase + (size_t)e * 32 * S_LEN + lv + kv0;
                    vf[2 * e]     = *(const f16x8*)(vp);
                    vf[2 * e + 1] = *(const f16x8*)(vp + 16);
                }
            }

            // --- K fragments from swizzled LDS (before issuing next fills)
            f16x8 kf[8];
            if (act) {
                const char* kt = (const char*)&Kst[role * 2 + p][0];
#pragma unroll
                for (int m = 0; m < 8; ++m) {
                    const int L = q * 256 + m * 32 + hi * 16;
                    kf[m] = *(const f16x8*)(kt + (L ^ swq));
                }
            }

            // --- issue async K fills for iteration it+1 (opposite parity)
            if (it + 1 < I)
                stage_k4(kbase, (char*)Kst, w, lane, p ^ 1, it + 1, jlock);

            if (act) {
                // --- S^T = K · Q^T  (two chains)
                f32x16 s0, s1;
#pragma unroll
                for (int i = 0; i < 16; ++i) { s0[i] = 0.f; s1[i] = 0.f; }
                __builtin_amdgcn_s_setprio(1);
#pragma unroll
                for (int m = 0; m < 8; m += 2) {
                    s0 = __builtin_amdgcn_mfma_f32_32x32x16_f16(kf[m],     qf[m],     s0, 0, 0, 0);
                    s1 = __builtin_amdgcn_mfma_f32_32x32x16_f16(kf[m + 1], qf[m + 1], s1, 0, 0, 0);
                }
                __builtin_amdgcn_s_setprio(0);

                f32x16 sv = s0 + s1;

                // --- causal mask (diagonal tile only)
                if (kv0 == q0w) {
#pragma unroll
                    for (int i = 0; i < 16; ++i) {
                        const int krel = (i & 3) + 8 * (i >> 2) + 4 * hi;
                        if (kv0 + krel > q_abs) sv[i] = -1e30f;
                    }
                }

                // --- in-register online softmax (per-lane = one q-row), exp2
                float t0 = fmaxf(sv[0], sv[1]),  t1 = fmaxf(sv[2], sv[3]);
                float t2 = fmaxf(sv[4], sv[5]),  t3 = fmaxf(sv[6], sv[7]);
                float t4 = fmaxf(sv[8], sv[9]),  t5 = fmaxf(sv[10], sv[11]);
                float t6 = fmaxf(sv[12], sv[13]), t7 = fmaxf(sv[14], sv[15]);
                t0 = fmaxf(t0, t1); t2 = fmaxf(t2, t3);
                t4 = fmaxf(t4, t5); t6 = fmaxf(t6, t7);
                float tm = fmaxf(fmaxf(t0, t2), fmaxf(t4, t6));
                tm = fmaxf(tm, __shfl_xor(tm, 32, 64));

                // defer-max (T13): rescale only when max grew by > 8
                if (!__all(tm - m_run <= 8.0f)) {
                    const float mnew = fmaxf(m_run, tm);
                    const float corr = exp2f(m_run - mnew);
                    l_run *= corr;
#pragma unroll
                    for (int e = 0; e < 4; ++e)
#pragma unroll
                        for (int i = 0; i < 16; ++i) acc[e][i] *= corr;
                    m_run = mnew;
                }

#pragma unroll
                for (int i = 0; i < 16; ++i) sv[i] = exp2f(sv[i] - m_run);
                float r0 = (sv[0] + sv[1]) + (sv[2] + sv[3]);
                float r1 = (sv[4] + sv[5]) + (sv[6] + sv[7]);
                float r2 = (sv[8] + sv[9]) + (sv[10] + sv[11]);
                float r3 = (sv[12] + sv[13]) + (sv[14] + sv[15]);
                float rs = (r0 + r1) + (r2 + r3);

                // --- P^T pack + cross-half redistribution
                unsigned u0 = __builtin_bit_cast(unsigned, __builtin_amdgcn_cvt_pkrtz(sv[0],  sv[1]));
                unsigned u1 = __builtin_bit_cast(unsigned, __builtin_amdgcn_cvt_pkrtz(sv[2],  sv[3]));
                unsigned u2 = __builtin_bit_cast(unsigned, __builtin_amdgcn_cvt_pkrtz(sv[4],  sv[5]));
                unsigned u3 = __builtin_bit_cast(unsigned, __builtin_amdgcn_cvt_pkrtz(sv[6],  sv[7]));
                unsigned u4 = __builtin_bit_cast(unsigned, __builtin_amdgcn_cvt_pkrtz(sv[8],  sv[9]));
                unsigned u5 = __builtin_bit_cast(unsigned, __builtin_amdgcn_cvt_pkrtz(sv[10], sv[11]));
                unsigned u6 = __builtin_bit_cast(unsigned, __builtin_amdgcn_cvt_pkrtz(sv[12], sv[13]));
                unsigned u7 = __builtin_bit_cast(unsigned, __builtin_amdgcn_cvt_pkrtz(sv[14], sv[15]));
                permswap(u0, u2); permswap(u1, u3);
                permswap(u4, u6); permswap(u5, u7);
                union uf8 { unsigned w[4]; f16x8 v; };
                uf8 p0; p0.w[0] = u0; p0.w[1] = u1; p0.w[2] = u2; p0.w[3] = u3;
                uf8 p1; p1.w[0] = u4; p1.w[1] = u5; p1.w[2] = u6; p1.w[3] = u7;

                // --- O^T += V^T · P^T
                __builtin_amdgcn_s_setprio(1);
#pragma unroll
                for (int e = 0; e < 4; ++e) {
                    acc[e] = __builtin_amdgcn_mfma_f32_32x32x16_f16(vf[2 * e],     p0.v, acc[e], 0, 0, 0);
                    acc[e] = __builtin_amdgcn_mfma_f32_32x32x16_f16(vf[2 * e + 1], p1.v, acc[e], 0, 0, 0);
                }
                __builtin_amdgcn_s_setprio(0);

                // --- cross-half sum overlaps the MFMA pipe
                rs += __shfl_xor(rs, 32, 64);
                l_run += rs;
            }
        }

        // --- 4-way KV-split combine (R8-verified pattern): roles 1-3 write
        //     partial (m,l,O); role 0 merges all 4 and stores.
        if (role != 0) {
            if (hi == 0) {
                mlbuf[qsub][role - 1][0][q] = m_run;
                mlbuf[qsub][role - 1][1][q] = l_run;
            }
#pragma unroll
            for (int e = 0; e < 4; ++e)
#pragma unroll
                for (int i = 0; i < 16; ++i) {
                    const int erow = e * 32 + (i & 3) + 8 * (i >> 2) + 4 * hi;
                    obuf[qsub][role - 1][q][erow] = (_Float16)acc[e][i];
                }
        }
        __syncthreads();
        if (role == 0) {
            const float m1 = mlbuf[qsub][0][0][q], l1 = mlbuf[qsub][0][1][q];
            const float m2 = mlbuf[qsub][1][0][q], l2 = mlbuf[qsub][1][1][q];
            const float m3 = mlbuf[qsub][2][0][q], l3 = mlbuf[qsub][2][1][q];
            const float ms = fmaxf(fmaxf(m_run, m1), fmaxf(m2, m3));
            const float c0 = exp2f(m_run - ms);
            const float c1 = exp2f(m1 - ms);
            const float c2 = exp2f(m2 - ms);
            const float c3 = exp2f(m3 - ms);
            const float rinv = 1.0f / (l_run * c0 + l1 * c1 + l2 * c2 + l3 * c3);
            float* orow = out + (size_t)q_abs * (NHEAD * DHEAD) + h * DHEAD;
#pragma unroll
            for (int e = 0; e < 4; ++e) {
#pragma unroll
                for (int g = 0; g < 4; ++g) {
                    f32x4 vv;
#pragma unroll
                    for (int c = 0; c < 4; ++c) {
                        const int i = g * 4 + c;
                        const int erow = e * 32 + 8 * g + 4 * hi + c;
                        vv[c] = (acc[e][i] * c0
                                 + (float)obuf[qsub][0][q][erow] * c1
                                 + (float)obuf[qsub][1][q][erow] * c2
                                 + (float)obuf[qsub][2][q][erow] * c3) * rinv;
                    }
                    *(f32x4*)(orow + e * 32 + 8 * g + 4 * hi) = vv;
                }
            }
        }
        // merge reads must finish before next phase's staging overwrites state
        __syncthreads();
    }
}

// ---------------------------------------------------------------------------
extern "C" void kernel_launch(void* const* d_in, const int* in_sizes, int n_in,
                              void* d_out, int out_size, void* d_ws, size_t ws_size,
                              hipStream_t stream) {
    const float* q_in = (const float*)d_in[0];
    const float* k_in = (const float*)d_in[1];
    const float* v_in = (const float*)d_in[2];
    // d_in[3] = attention_mask (strict causal triu) -- implemented analytically
    const float* w_qk = (const float*)d_in[4];
    const float* w_v  = (const float*)d_in[5];
    float* out = (float*)d_out;

    const size_t mat_elems = (size_t)NHEAD * S_LEN * DHEAD;
    const size_t w_elems   = (size_t)NHEAD * DHEAD * DHEAD;
    _Float16* Qp   = (_Float16*)d_ws;
    _Float16* Kp   = Qp + mat_elems;
    _Float16* Vt   = Kp + mat_elems;
    _Float16* Wqkt = Vt + mat_elems;
    _Float16* Wvt  = Wqkt + w_elems;

    transpose_w_kernel<<<dim3(16, NHEAD, 2), dim3(256), 0, stream>>>(w_qk, w_v, Wqkt, Wvt);
    proj_kernel<<<dim3(NHEAD * 32, 2), dim3(256), 0, stream>>>(q_in, k_in, v_in, Wqkt, Wvt, Qp, Kp, Vt);
    attn_kernel<<<dim3(16, NHEAD), dim3(512), 0, stream>>>(Qp, Kp, Vt, out);
}

// Round 19
// 86.880 us; speedup vs baseline: 1.0622x; 1.0622x over previous
//
#include <hip/hip_runtime.h>
#include <hip/hip_bf16.h>
#include <math.h>

#define S_LEN 2048
#define NHEAD 16
#define DHEAD 128

typedef __attribute__((ext_vector_type(8)))  _Float16 f16x8;
typedef __attribute__((ext_vector_type(4)))  _Float16 f16x4;
typedef __attribute__((ext_vector_type(4)))  float    f32x4;
typedef __attribute__((ext_vector_type(16))) float    f32x16;

// vdst.hi32lanes <-> vsrc.lo32lanes   (HW-verified by round-2 passing)
__device__ __forceinline__ void permswap(unsigned &a, unsigned &b) {
    asm volatile("v_permlane32_swap_b32 %0, %1" : "+v"(a), "+v"(b));
}

// async global->LDS, 16B per lane; LDS dest = wave-uniform base + lane*16
typedef __attribute__((address_space(3))) unsigned int lds_u32;
typedef __attribute__((address_space(1))) const unsigned int glb_u32;
__device__ __forceinline__ void gload16(const void* g, void* l) {
    __builtin_amdgcn_global_load_lds((glb_u32*)g, (lds_u32*)l, 16, 0, 0);
}

// ---------------------------------------------------------------------------
// Kernel 1: transpose the two SVD weight mats [H][d][e] f32 -> [H][e][d] f16
// ---------------------------------------------------------------------------
__global__ __launch_bounds__(256) void transpose_w_kernel(
    const float* __restrict__ w_qk, const float* __restrict__ w_v,
    _Float16* __restrict__ wqk_t, _Float16* __restrict__ wv_t)
{
    __shared__ float tile[32][33];
    const int mat = blockIdx.z;
    const int h   = blockIdx.y;
    const int t0  = blockIdx.x;
    const int dt  = (t0 >> 2) * 32;
    const int et  = (t0 & 3) * 32;
    const float* src = (mat ? w_v : w_qk) + (size_t)h * DHEAD * DHEAD;
    _Float16*   dst = (mat ? wv_t : wqk_t) + (size_t)h * DHEAD * DHEAD;
    const int tx = threadIdx.x & 31, ty = threadIdx.x >> 5;
#pragma unroll
    for (int k = 0; k < 4; ++k)
        tile[ty + 8 * k][tx] = src[(size_t)(dt + ty + 8 * k) * DHEAD + et + tx];
    __syncthreads();
#pragma unroll
    for (int k = 0; k < 4; ++k)
        dst[(size_t)(et + ty + 8 * k) * DHEAD + dt + tx] = (_Float16)tile[tx][ty + 8 * k];
}

// ---------------------------------------------------------------------------
// Kernel 2: per-head projection via MFMA 16x16x32 f16 (round-8-verified math)
// R19: LDS-SHARED X. Block = 512 thr (8 waves), grid (NHEAD*32):
//   Phase A: all threads cooperatively load the block's X slice (64 rows x
//   3 mats, fp32) ONCE, convert to f16 into LDS (52 KB, 272B row stride).
//   Phase B: wave w: row-group rw = w&3 (16 rows), column half ch = w>>2
//   (4 cbs). A-frags come from LDS; rest identical to the verified body.
// 512 blocks x 8 waves = 4 waves/SIMD (2x R17) with X traffic unchanged.
//   Qp[h][s][e] = (X_q[s] @ W_qk) * log2(e)/sqrt(128)  (f16; exp2 domain)
//   Kp[h][s][e] =  X_k[s] @ W_qk                       (f16)
//   Vt[h][e][s] =  X_v[s] @ W_v (plain transposed)     (f16)
// ---------------------------------------------------------------------------
__global__ __launch_bounds__(512, 4) void proj_kernel(
    const float* __restrict__ q_in, const float* __restrict__ k_in,
    const float* __restrict__ v_in,
    const _Float16* __restrict__ wqk_t, const _Float16* __restrict__ wv_t,
    _Float16* __restrict__ Qp, _Float16* __restrict__ Kp, _Float16* __restrict__ Vt)
{
    __shared__ _Float16 xs[3][64][136];   // 272B row stride (16B-aligned), 52 KB

    const int h   = blockIdx.x >> 5;
    const int rb  = blockIdx.x & 31;
    const int tid = threadIdx.x;

    // ---- Phase A: cooperative X -> LDS (f16), traffic exactly 1x ----
#pragma unroll
    for (int m = 0; m < 3; ++m) {
        const float* xin = (m == 0) ? q_in : (m == 1) ? k_in : v_in;
#pragma unroll
        for (int k = 0; k < 4; ++k) {
            const int v   = tid + k * 512;       // vec4 index, 2048 per mat
            const int row = v >> 5;              // 32 vec4 per 128-f32 row
            const int c4  = v & 31;
            const f32x4 x = *(const f32x4*)(xin +
                ((size_t)(rb * 64 + row) * NHEAD + h) * DHEAD + c4 * 4);
            f16x4 xh;
#pragma unroll
            for (int i = 0; i < 4; ++i) xh[i] = (_Float16)x[i];
            *(f16x4*)&xs[m][row][c4 * 4] = xh;
        }
    }
    __syncthreads();

    // ---- Phase B: 8 waves = 4 row-groups x 2 column halves ----
    const int w    = tid >> 6;
    const int lane = tid & 63;
    const int r16  = lane & 15;
    const int kg   = lane >> 4;
    const int rw   = w & 3;
    const int ch   = w >> 2;
    const int s_base = rb * 64 + rw * 16;
    // 1/sqrt(128) * log2(e)  -- softmax runs in exp2 domain (R5/R10-verified)
    const float INV_NORM = 0.12752211758f;

    f16x8 aq[4], ak[4], av[4];
#pragma unroll
    for (int kb = 0; kb < 4; ++kb) {
        const int d0 = kb * 32 + kg * 8;
        aq[kb] = *(const f16x8*)&xs[0][rw * 16 + r16][d0];
        ak[kb] = *(const f16x8*)&xs[1][rw * 16 + r16][d0];
        av[kb] = *(const f16x8*)&xs[2][rw * 16 + r16][d0];
    }

    const _Float16* wq_h = wqk_t + (size_t)h * DHEAD * DHEAD;
    const _Float16* wv_h = wv_t  + (size_t)h * DHEAD * DHEAD;

#pragma unroll 2
    for (int cc = 0; cc < 4; ++cc) {
        const int cb = ch * 4 + cc;
        f32x4 accq = {0.f, 0.f, 0.f, 0.f};
        f32x4 acck = {0.f, 0.f, 0.f, 0.f};
        f32x4 accv = {0.f, 0.f, 0.f, 0.f};
        const int c = cb * 16 + r16;
#pragma unroll
        for (int kb = 0; kb < 4; ++kb) {
            const f16x8 bqk = *(const f16x8*)(wq_h + (size_t)c * DHEAD + kb * 32 + kg * 8);
            const f16x8 bv  = *(const f16x8*)(wv_h + (size_t)c * DHEAD + kb * 32 + kg * 8);
            // swapped: A = weight (rows = e), B = X (cols = s)
            accq = __builtin_amdgcn_mfma_f32_16x16x32_f16(bqk, aq[kb], accq, 0, 0, 0);
            acck = __builtin_amdgcn_mfma_f32_16x16x32_f16(bqk, ak[kb], acck, 0, 0, 0);
            accv = __builtin_amdgcn_mfma_f32_16x16x32_f16(av[kb], bv,  accv, 0, 0, 0);
        }
        // Q/K: D row = e = cb*16 + kg*4 + jj, col = s = s_base + r16
        f16x4 qv, kv4;
#pragma unroll
        for (int jj = 0; jj < 4; ++jj) {
            qv[jj]  = (_Float16)(accq[jj] * INV_NORM);
            kv4[jj] = (_Float16)acck[jj];
        }
        *(f16x4*)(Qp + ((size_t)h * S_LEN + s_base + r16) * DHEAD + cb * 16 + kg * 4) = qv;
        *(f16x4*)(Kp + ((size_t)h * S_LEN + s_base + r16) * DHEAD + cb * 16 + kg * 4) = kv4;
        // V: D row = s = s_base + kg*4 + jj, col = e = c  (plain transpose)
        f16x4 vvv;
#pragma unroll
        for (int jj = 0; jj < 4; ++jj) vvv[jj] = (_Float16)accv[jj];
        *(f16x4*)(Vt + ((size_t)h * DHEAD + c) * S_LEN + s_base + kg * 4) = vvv;
    }
}

// ---------------------------------------------------------------------------
// Kernel 3: causal flash attention — R17-verified (byte-identical):
// sequential-phase schedule + head-locality XCD swizzle (FETCH 97->12 MB).
// Grid (16, H); block 512 = 8 waves: role = w&3, qsub = w>>2.
// Phase 0: q-tile t = 31-x (heavy); phase 1: q-tile t = x (light).
// ---------------------------------------------------------------------------
__device__ __forceinline__ void stage_k4(const _Float16* kbase, char* kst,
                                         int w, int lane, int par, int inext,
                                         int jmax_lock) {
#pragma unroll
    for (int cidx = 0; cidx < 4; ++cidx) {
        const int c    = 4 * w + cidx;        // 32 chunks = 4 tiles of 8KB
        const int slot = c >> 3;              // tile slot 0..3 (= role)
        const int cc   = c & 7;               // 1KB chunk within tile
        const int jn   = 4 * inext + slot;
        if (jn < jmax_lock) {
            const int A    = cc * 1024 + lane * 16;          // linear tile offset
            const int srcO = A ^ (((A >> 8) & 15) << 4);     // inverse swizzle
            const char* g  = (const char*)kbase + (size_t)jn * 8192 + srcO;
            char*       l  = kst + (size_t)(slot * 2 + par) * 8192
                                 + cc * 1024;                // wave-uniform base
            gload16(g, l);
        }
    }
}

__global__ __launch_bounds__(512, 2) void attn_kernel(
    const _Float16* __restrict__ Qp, const _Float16* __restrict__ Kp,
    const _Float16* __restrict__ Vt, float* __restrict__ out)
{
    __shared__ _Float16 Kst[8][4096];        // [slot*2+parity] 32x128 f16 = 64 KB
    __shared__ _Float16 obuf[2][3][32][132]; // [qsub][role-1] partials ~50.7 KB
    __shared__ float    mlbuf[2][3][2][32];

    // --- head-locality XCD swizzle (T1): id = x + 16h round-robins XCDs by
    //     id&7; pick h' = id&7 (+8) so each XCD serves exactly 2 heads.
    const int id  = blockIdx.x + (blockIdx.y << 4);
    const int xb  = id >> 4;
    const int h   = (id & 7) + 8 * ((id >> 3) & 1);

    const int w    = threadIdx.x >> 6;
    const int lane = threadIdx.x & 63;
    const int q    = lane & 31;
    const int hi   = lane >> 5;

    const int role = w & 3;
    const int qsub = w >> 2;

    const _Float16* kbase = Kp + (size_t)h * S_LEN * DHEAD;
    const _Float16* vbase = Vt + (size_t)h * DHEAD * S_LEN;

    const int lqk = q * DHEAD + hi * 8;   // lane offset in row-major [s][d]
    const int lv  = q * S_LEN + hi * 8;   // lane offset in [e][s]
    const int swq = (q & 15) << 4;        // read-side swizzle for K LDS

    for (int ph = 0; ph < 2; ++ph) {
        const int t     = ph ? xb : (31 - xb);
        const int q0w   = t * 64 + qsub * 32;
        const int jmax  = 2 * t + 1 + qsub;
        const int jlock = 2 * t + 2;            // block-uniform staging bound
        const int I     = (jlock + 3) >> 2;     // lockstep iterations
        const int q_abs = q0w + q;

        // Q fragments (B-operand): lane holds Q[q][16m + hi*8 + i]
        const _Float16* qbase = Qp + ((size_t)h * S_LEN + q0w) * DHEAD;
        f16x8 qf[8];
#pragma unroll
        for (int m = 0; m < 8; ++m)
            qf[m] = *(const f16x8*)(qbase + lqk + m * 16);

        // O^T accumulators: acc[eb] -> e = eb*32 + (i&3)+8*(i>>2)+4*hi, col q
        f32x16 acc[4];
#pragma unroll
        for (int e = 0; e < 4; ++e)
#pragma unroll
            for (int i = 0; i < 16; ++i) acc[e][i] = 0.f;
        float m_run = -1e30f, l_run = 0.f;

        // prologue: stage K tiles {0..3} into parity 0
        stage_k4(kbase, (char*)Kst, w, lane, 0, 0, jlock);

        int p = 0;
        for (int it = 0; it < I; ++it, p ^= 1) {
            __syncthreads();   // vmcnt(0) drain: fills for 'it' visible

            const int j   = 4 * it + role;
            const bool act = (j < jmax);
            const int kv0 = j * 32;

            // --- V fragments FIRST (L2 latency hides under ds_read+QK+softmax)
            f16x8 vf[8];
            if (act) {
#pragma unroll
                for (int e = 0; e < 4; ++e) {
                    const _Float16* vp = vbase + (size_t)e * 32 * S_LEN + lv + kv0;
                    vf[2 * e]     = *(const f16x8*)(vp);
                    vf[2 * e + 1] = *(const f16x8*)(vp + 16);
                }
            }

            // --- K fragments from swizzled LDS (before issuing next fills)
            f16x8 kf[8];
            if (act) {
                const char* kt = (const char*)&Kst[role * 2 + p][0];
#pragma unroll
                for (int m = 0; m < 8; ++m) {
                    const int L = q * 256 + m * 32 + hi * 16;
                    kf[m] = *(const f16x8*)(kt + (L ^ swq));
                }
            }

            // --- issue async K fills for iteration it+1 (opposite parity)
            if (it + 1 < I)
                stage_k4(kbase, (char*)Kst, w, lane, p ^ 1, it + 1, jlock);

            if (act) {
                // --- S^T = K · Q^T  (two chains)
                f32x16 s0, s1;
#pragma unroll
                for (int i = 0; i < 16; ++i) { s0[i] = 0.f; s1[i] = 0.f; }
                __builtin_amdgcn_s_setprio(1);
#pragma unroll
                for (int m = 0; m < 8; m += 2) {
                    s0 = __builtin_amdgcn_mfma_f32_32x32x16_f16(kf[m],     qf[m],     s0, 0, 0, 0);
                    s1 = __builtin_amdgcn_mfma_f32_32x32x16_f16(kf[m + 1], qf[m + 1], s1, 0, 0, 0);
                }
                __builtin_amdgcn_s_setprio(0);

                f32x16 sv = s0 + s1;

                // --- causal mask (diagonal tile only)
                if (kv0 == q0w) {
#pragma unroll
                    for (int i = 0; i < 16; ++i) {
                        const int krel = (i & 3) + 8 * (i >> 2) + 4 * hi;
                        if (kv0 + krel > q_abs) sv[i] = -1e30f;
                    }
                }

                // --- in-register online softmax (per-lane = one q-row), exp2
                float t0 = fmaxf(sv[0], sv[1]),  t1 = fmaxf(sv[2], sv[3]);
                float t2 = fmaxf(sv[4], sv[5]),  t3 = fmaxf(sv[6], sv[7]);
                float t4 = fmaxf(sv[8], sv[9]),  t5 = fmaxf(sv[10], sv[11]);
                float t6 = fmaxf(sv[12], sv[13]), t7 = fmaxf(sv[14], sv[15]);
                t0 = fmaxf(t0, t1); t2 = fmaxf(t2, t3);
                t4 = fmaxf(t4, t5); t6 = fmaxf(t6, t7);
                float tm = fmaxf(fmaxf(t0, t2), fmaxf(t4, t6));
                tm = fmaxf(tm, __shfl_xor(tm, 32, 64));

                // defer-max (T13): rescale only when max grew by > 8
                if (!__all(tm - m_run <= 8.0f)) {
                    const float mnew = fmaxf(m_run, tm);
                    const float corr = exp2f(m_run - mnew);
                    l_run *= corr;
#pragma unroll
                    for (int e = 0; e < 4; ++e)
#pragma unroll
                        for (int i = 0; i < 16; ++i) acc[e][i] *= corr;
                    m_run = mnew;
                }

#pragma unroll
                for (int i = 0; i < 16; ++i) sv[i] = exp2f(sv[i] - m_run);
                float r0 = (sv[0] + sv[1]) + (sv[2] + sv[3]);
                float r1 = (sv[4] + sv[5]) + (sv[6] + sv[7]);
                float r2 = (sv[8] + sv[9]) + (sv[10] + sv[11]);
                float r3 = (sv[12] + sv[13]) + (sv[14] + sv[15]);
                float rs = (r0 + r1) + (r2 + r3);

                // --- P^T pack + cross-half redistribution
                unsigned u0 = __builtin_bit_cast(unsigned, __builtin_amdgcn_cvt_pkrtz(sv[0],  sv[1]));
                unsigned u1 = __builtin_bit_cast(unsigned, __builtin_amdgcn_cvt_pkrtz(sv[2],  sv[3]));
                unsigned u2 = __builtin_bit_cast(unsigned, __builtin_amdgcn_cvt_pkrtz(sv[4],  sv[5]));
                unsigned u3 = __builtin_bit_cast(unsigned, __builtin_amdgcn_cvt_pkrtz(sv[6],  sv[7]));
                unsigned u4 = __builtin_bit_cast(unsigned, __builtin_amdgcn_cvt_pkrtz(sv[8],  sv[9]));
                unsigned u5 = __builtin_bit_cast(unsigned, __builtin_amdgcn_cvt_pkrtz(sv[10], sv[11]));
                unsigned u6 = __builtin_bit_cast(unsigned, __builtin_amdgcn_cvt_pkrtz(sv[12], sv[13]));
                unsigned u7 = __builtin_bit_cast(unsigned, __builtin_amdgcn_cvt_pkrtz(sv[14], sv[15]));
                permswap(u0, u2); permswap(u1, u3);
                permswap(u4, u6); permswap(u5, u7);
                union uf8 { unsigned w[4]; f16x8 v; };
                uf8 p0; p0.w[0] = u0; p0.w[1] = u1; p0.w[2] = u2; p0.w[3] = u3;
                uf8 p1; p1.w[0] = u4; p1.w[1] = u5; p1.w[2] = u6; p1.w[3] = u7;

                // --- O^T += V^T · P^T
                __builtin_amdgcn_s_setprio(1);
#pragma unroll
                for (int e = 0; e < 4; ++e) {
                    acc[e] = __builtin_amdgcn_mfma_f32_32x32x16_f16(vf[2 * e],     p0.v, acc[e], 0, 0, 0);
                    acc[e] = __builtin_amdgcn_mfma_f32_32x32x16_f16(vf[2 * e + 1], p1.v, acc[e], 0, 0, 0);
                }
                __builtin_amdgcn_s_setprio(0);

                // --- cross-half sum overlaps the MFMA pipe
                rs += __shfl_xor(rs, 32, 64);
                l_run += rs;
            }
        }

        // --- 4-way KV-split combine (R8-verified pattern): roles 1-3 write
        //     partial (m,l,O); role 0 merges all 4 and stores.
        if (role != 0) {
            if (hi == 0) {
                mlbuf[qsub][role - 1][0][q] = m_run;
                mlbuf[qsub][role - 1][1][q] = l_run;
            }
#pragma unroll
            for (int e = 0; e < 4; ++e)
#pragma unroll
                for (int i = 0; i < 16; ++i) {
                    const int erow = e * 32 + (i & 3) + 8 * (i >> 2) + 4 * hi;
                    obuf[qsub][role - 1][q][erow] = (_Float16)acc[e][i];
                }
        }
        __syncthreads();
        if (role == 0) {
            const float m1 = mlbuf[qsub][0][0][q], l1 = mlbuf[qsub][0][1][q];
            const float m2 = mlbuf[qsub][1][0][q], l2 = mlbuf[qsub][1][1][q];
            const float m3 = mlbuf[qsub][2][0][q], l3 = mlbuf[qsub][2][1][q];
            const float ms = fmaxf(fmaxf(m_run, m1), fmaxf(m2, m3));
            const float c0 = exp2f(m_run - ms);
            const float c1 = exp2f(m1 - ms);
            const float c2 = exp2f(m2 - ms);
            const float c3 = exp2f(m3 - ms);
            const float rinv = 1.0f / (l_run * c0 + l1 * c1 + l2 * c2 + l3 * c3);
            float* orow = out + (size_t)q_abs * (NHEAD * DHEAD) + h * DHEAD;
#pragma unroll
            for (int e = 0; e < 4; ++e) {
#pragma unroll
                for (int g = 0; g < 4; ++g) {
                    f32x4 vv;
#pragma unroll
                    for (int c = 0; c < 4; ++c) {
                        const int i = g * 4 + c;
                        const int erow = e * 32 + 8 * g + 4 * hi + c;
                        vv[c] = (acc[e][i] * c0
                                 + (float)obuf[qsub][0][q][erow] * c1
                                 + (float)obuf[qsub][1][q][erow] * c2
                                 + (float)obuf[qsub][2][q][erow] * c3) * rinv;
                    }
                    *(f32x4*)(orow + e * 32 + 8 * g + 4 * hi) = vv;
                }
            }
        }
        // merge reads must finish before next phase's staging overwrites state
        __syncthreads();
    }
}

// ---------------------------------------------------------------------------
extern "C" void kernel_launch(void* const* d_in, const int* in_sizes, int n_in,
                              void* d_out, int out_size, void* d_ws, size_t ws_size,
                              hipStream_t stream) {
    const float* q_in = (const float*)d_in[0];
    const float* k_in = (const float*)d_in[1];
    const float* v_in = (const float*)d_in[2];
    // d_in[3] = attention_mask (strict causal triu) -- implemented analytically
    const float* w_qk = (const float*)d_in[4];
    const float* w_v  = (const float*)d_in[5];
    float* out = (float*)d_out;

    const size_t mat_elems = (size_t)NHEAD * S_LEN * DHEAD;
    const size_t w_elems   = (size_t)NHEAD * DHEAD * DHEAD;
    _Float16* Qp   = (_Float16*)d_ws;
    _Float16* Kp   = Qp + mat_elems;
    _Float16* Vt   = Kp + mat_elems;
    _Float16* Wqkt = Vt + mat_elems;
    _Float16* Wvt  = Wqkt + w_elems;

    transpose_w_kernel<<<dim3(16, NHEAD, 2), dim3(256), 0, stream>>>(w_qk, w_v, Wqkt, Wvt);
    proj_kernel<<<dim3(NHEAD * 32), dim3(512), 0, stream>>>(q_in, k_in, v_in, Wqkt, Wvt, Qp, Kp, Vt);
    attn_kernel<<<dim3(16, NHEAD), dim3(512), 0, stream>>>(Qp, Kp, Vt, out);
}

// Round 20
// 86.739 us; speedup vs baseline: 1.0640x; 1.0016x over previous
//
#include <hip/hip_runtime.h>
#include <hip/hip_bf16.h>
#include <math.h>

#define S_LEN 2048
#define NHEAD 16
#define DHEAD 128

typedef __attribute__((ext_vector_type(8)))  _Float16 f16x8;
typedef __attribute__((ext_vector_type(4)))  _Float16 f16x4;
typedef __attribute__((ext_vector_type(4)))  float    f32x4;
typedef __attribute__((ext_vector_type(16))) float    f32x16;

// vdst.hi32lanes <-> vsrc.lo32lanes   (HW-verified by round-2 passing)
__device__ __forceinline__ void permswap(unsigned &a, unsigned &b) {
    asm volatile("v_permlane32_swap_b32 %0, %1" : "+v"(a), "+v"(b));
}

// async global->LDS, 16B per lane; LDS dest = wave-uniform base + lane*16
typedef __attribute__((address_space(3))) unsigned int lds_u32;
typedef __attribute__((address_space(1))) const unsigned int glb_u32;
__device__ __forceinline__ void gload16(const void* g, void* l) {
    __builtin_amdgcn_global_load_lds((glb_u32*)g, (lds_u32*)l, 16, 0, 0);
}

// ---------------------------------------------------------------------------
// Kernel 1: transpose the two SVD weight mats [H][d][e] f32 -> [H][e][d] f16
// ---------------------------------------------------------------------------
__global__ __launch_bounds__(256) void transpose_w_kernel(
    const float* __restrict__ w_qk, const float* __restrict__ w_v,
    _Float16* __restrict__ wqk_t, _Float16* __restrict__ wv_t)
{
    __shared__ float tile[32][33];
    const int mat = blockIdx.z;
    const int h   = blockIdx.y;
    const int t0  = blockIdx.x;
    const int dt  = (t0 >> 2) * 32;
    const int et  = (t0 & 3) * 32;
    const float* src = (mat ? w_v : w_qk) + (size_t)h * DHEAD * DHEAD;
    _Float16*   dst = (mat ? wv_t : wqk_t) + (size_t)h * DHEAD * DHEAD;
    const int tx = threadIdx.x & 31, ty = threadIdx.x >> 5;
#pragma unroll
    for (int k = 0; k < 4; ++k)
        tile[ty + 8 * k][tx] = src[(size_t)(dt + ty + 8 * k) * DHEAD + et + tx];
    __syncthreads();
#pragma unroll
    for (int k = 0; k < 4; ++k)
        dst[(size_t)(et + ty + 8 * k) * DHEAD + dt + tx] = (_Float16)tile[tx][ty + 8 * k];
}

// ---------------------------------------------------------------------------
// Kernel 2: per-head projection via MFMA 16x16x32 f16 (round-8-verified math)
// R19 structure (LDS-shared X, 8 waves) + R20 block remap for DRAM locality:
//   h = id & 15, rb = id >> 4 -> the 16 temporally-adjacent blocks cover all
//   heads of the SAME 64 rows = contiguous 512 KB of X (sequential pages),
//   instead of 512B chunks strided 8KB.
//   Qp[h][s][e] = (X_q[s] @ W_qk) * log2(e)/sqrt(128)  (f16; exp2 domain)
//   Kp[h][s][e] =  X_k[s] @ W_qk                       (f16)
//   Vt[h][e][s] =  X_v[s] @ W_v (plain transposed)     (f16)
// ---------------------------------------------------------------------------
__global__ __launch_bounds__(512, 4) void proj_kernel(
    const float* __restrict__ q_in, const float* __restrict__ k_in,
    const float* __restrict__ v_in,
    const _Float16* __restrict__ wqk_t, const _Float16* __restrict__ wv_t,
    _Float16* __restrict__ Qp, _Float16* __restrict__ Kp, _Float16* __restrict__ Vt)
{
    __shared__ _Float16 xs[3][64][136];   // 272B row stride (16B-aligned), 52 KB

    const int h   = blockIdx.x & 15;      // R20: adjacent blocks = same rows,
    const int rb  = blockIdx.x >> 4;      //      all heads -> contiguous DRAM
    const int tid = threadIdx.x;

    // ---- Phase A: cooperative X -> LDS (f16), traffic exactly 1x ----
#pragma unroll
    for (int m = 0; m < 3; ++m) {
        const float* xin = (m == 0) ? q_in : (m == 1) ? k_in : v_in;
#pragma unroll
        for (int k = 0; k < 4; ++k) {
            const int v   = tid + k * 512;       // vec4 index, 2048 per mat
            const int row = v >> 5;              // 32 vec4 per 128-f32 row
            const int c4  = v & 31;
            const f32x4 x = *(const f32x4*)(xin +
                ((size_t)(rb * 64 + row) * NHEAD + h) * DHEAD + c4 * 4);
            f16x4 xh;
#pragma unroll
            for (int i = 0; i < 4; ++i) xh[i] = (_Float16)x[i];
            *(f16x4*)&xs[m][row][c4 * 4] = xh;
        }
    }
    __syncthreads();

    // ---- Phase B: 8 waves = 4 row-groups x 2 column halves ----
    const int w    = tid >> 6;
    const int lane = tid & 63;
    const int r16  = lane & 15;
    const int kg   = lane >> 4;
    const int rw   = w & 3;
    const int ch   = w >> 2;
    const int s_base = rb * 64 + rw * 16;
    // 1/sqrt(128) * log2(e)  -- softmax runs in exp2 domain (R5/R10-verified)
    const float INV_NORM = 0.12752211758f;

    f16x8 aq[4], ak[4], av[4];
#pragma unroll
    for (int kb = 0; kb < 4; ++kb) {
        const int d0 = kb * 32 + kg * 8;
        aq[kb] = *(const f16x8*)&xs[0][rw * 16 + r16][d0];
        ak[kb] = *(const f16x8*)&xs[1][rw * 16 + r16][d0];
        av[kb] = *(const f16x8*)&xs[2][rw * 16 + r16][d0];
    }

    const _Float16* wq_h = wqk_t + (size_t)h * DHEAD * DHEAD;
    const _Float16* wv_h = wv_t  + (size_t)h * DHEAD * DHEAD;

#pragma unroll 2
    for (int cc = 0; cc < 4; ++cc) {
        const int cb = ch * 4 + cc;
        f32x4 accq = {0.f, 0.f, 0.f, 0.f};
        f32x4 acck = {0.f, 0.f, 0.f, 0.f};
        f32x4 accv = {0.f, 0.f, 0.f, 0.f};
        const int c = cb * 16 + r16;
#pragma unroll
        for (int kb = 0; kb < 4; ++kb) {
            const f16x8 bqk = *(const f16x8*)(wq_h + (size_t)c * DHEAD + kb * 32 + kg * 8);
            const f16x8 bv  = *(const f16x8*)(wv_h + (size_t)c * DHEAD + kb * 32 + kg * 8);
            // swapped: A = weight (rows = e), B = X (cols = s)
            accq = __builtin_amdgcn_mfma_f32_16x16x32_f16(bqk, aq[kb], accq, 0, 0, 0);
            acck = __builtin_amdgcn_mfma_f32_16x16x32_f16(bqk, ak[kb], acck, 0, 0, 0);
            accv = __builtin_amdgcn_mfma_f32_16x16x32_f16(av[kb], bv,  accv, 0, 0, 0);
        }
        // Q/K: D row = e = cb*16 + kg*4 + jj, col = s = s_base + r16
        f16x4 qv, kv4;
#pragma unroll
        for (int jj = 0; jj < 4; ++jj) {
            qv[jj]  = (_Float16)(accq[jj] * INV_NORM);
            kv4[jj] = (_Float16)acck[jj];
        }
        *(f16x4*)(Qp + ((size_t)h * S_LEN + s_base + r16) * DHEAD + cb * 16 + kg * 4) = qv;
        *(f16x4*)(Kp + ((size_t)h * S_LEN + s_base + r16) * DHEAD + cb * 16 + kg * 4) = kv4;
        // V: D row = s = s_base + kg*4 + jj, col = e = c  (plain transpose)
        f16x4 vvv;
#pragma unroll
        for (int jj = 0; jj < 4; ++jj) vvv[jj] = (_Float16)accv[jj];
        *(f16x4*)(Vt + ((size_t)h * DHEAD + c) * S_LEN + s_base + kg * 4) = vvv;
    }
}

// ---------------------------------------------------------------------------
// Kernel 3: causal flash attention — R17-verified (byte-identical):
// sequential-phase schedule + head-locality XCD swizzle (FETCH 97->12 MB).
// Grid (16, H); block 512 = 8 waves: role = w&3, qsub = w>>2.
// Phase 0: q-tile t = 31-x (heavy); phase 1: q-tile t = x (light).
// ---------------------------------------------------------------------------
__device__ __forceinline__ void stage_k4(const _Float16* kbase, char* kst,
                                         int w, int lane, int par, int inext,
                                         int jmax_lock) {
#pragma unroll
    for (int cidx = 0; cidx < 4; ++cidx) {
        const int c    = 4 * w + cidx;        // 32 chunks = 4 tiles of 8KB
        const int slot = c >> 3;              // tile slot 0..3 (= role)
        const int cc   = c & 7;               // 1KB chunk within tile
        const int jn   = 4 * inext + slot;
        if (jn < jmax_lock) {
            const int A    = cc * 1024 + lane * 16;          // linear tile offset
            const int srcO = A ^ (((A >> 8) & 15) << 4);     // inverse swizzle
            const char* g  = (const char*)kbase + (size_t)jn * 8192 + srcO;
            char*       l  = kst + (size_t)(slot * 2 + par) * 8192
                                 + cc * 1024;                // wave-uniform base
            gload16(g, l);
        }
    }
}

__global__ __launch_bounds__(512, 2) void attn_kernel(
    const _Float16* __restrict__ Qp, const _Float16* __restrict__ Kp,
    const _Float16* __restrict__ Vt, float* __restrict__ out)
{
    __shared__ _Float16 Kst[8][4096];        // [slot*2+parity] 32x128 f16 = 64 KB
    __shared__ _Float16 obuf[2][3][32][132]; // [qsub][role-1] partials ~50.7 KB
    __shared__ float    mlbuf[2][3][2][32];

    // --- head-locality XCD swizzle (T1): id = x + 16h round-robins XCDs by
    //     id&7; pick h' = id&7 (+8) so each XCD serves exactly 2 heads.
    const int id  = blockIdx.x + (blockIdx.y << 4);
    const int xb  = id >> 4;
    const int h   = (id & 7) + 8 * ((id >> 3) & 1);

    const int w    = threadIdx.x >> 6;
    const int lane = threadIdx.x & 63;
    const int q    = lane & 31;
    const int hi   = lane >> 5;

    const int role = w & 3;
    const int qsub = w >> 2;

    const _Float16* kbase = Kp + (size_t)h * S_LEN * DHEAD;
    const _Float16* vbase = Vt + (size_t)h * DHEAD * S_LEN;

    const int lqk = q * DHEAD + hi * 8;   // lane offset in row-major [s][d]
    const int lv  = q * S_LEN + hi * 8;   // lane offset in [e][s]
    const int swq = (q & 15) << 4;        // read-side swizzle for K LDS

    for (int ph = 0; ph < 2; ++ph) {
        const int t     = ph ? xb : (31 - xb);
        const int q0w   = t * 64 + qsub * 32;
        const int jmax  = 2 * t + 1 + qsub;
        const int jlock = 2 * t + 2;            // block-uniform staging bound
        const int I     = (jlock + 3) >> 2;     // lockstep iterations
        const int q_abs = q0w + q;

        // Q fragments (B-operand): lane holds Q[q][16m + hi*8 + i]
        const _Float16* qbase = Qp + ((size_t)h * S_LEN + q0w) * DHEAD;
        f16x8 qf[8];
#pragma unroll
        for (int m = 0; m < 8; ++m)
            qf[m] = *(const f16x8*)(qbase + lqk + m * 16);

        // O^T accumulators: acc[eb] -> e = eb*32 + (i&3)+8*(i>>2)+4*hi, col q
        f32x16 acc[4];
#pragma unroll
        for (int e = 0; e < 4; ++e)
#pragma unroll
            for (int i = 0; i < 16; ++i) acc[e][i] = 0.f;
        float m_run = -1e30f, l_run = 0.f;

        // prologue: stage K tiles {0..3} into parity 0
        stage_k4(kbase, (char*)Kst, w, lane, 0, 0, jlock);

        int p = 0;
        for (int it = 0; it < I; ++it, p ^= 1) {
            __syncthreads();   // vmcnt(0) drain: fills for 'it' visible

            const int j   = 4 * it + role;
            const bool act = (j < jmax);
            const int kv0 = j * 32;

            // --- V fragments FIRST (L2 latency hides under ds_read+QK+softmax)
            f16x8 vf[8];
            if (act) {
#pragma unroll
                for (int e = 0; e < 4; ++e) {
                    const _Float16* vp = vbase + (size_t)e * 32 * S_LEN + lv + kv0;
                    vf[2 * e]     = *(const f16x8*)(vp);
                    vf[2 * e + 1] = *(const f16x8*)(vp + 16);
                }
            }

            // --- K fragments from swizzled LDS (before issuing next fills)
            f16x8 kf[8];
            if (act) {
                const char* kt = (const char*)&Kst[role * 2 + p][0];
#pragma unroll
                for (int m = 0; m < 8; ++m) {
                    const int L = q * 256 + m * 32 + hi * 16;
                    kf[m] = *(const f16x8*)(kt + (L ^ swq));
                }
            }

            // --- issue async K fills for iteration it+1 (opposite parity)
            if (it + 1 < I)
                stage_k4(kbase, (char*)Kst, w, lane, p ^ 1, it + 1, jlock);

            if (act) {
                // --- S^T = K · Q^T  (two chains)
                f32x16 s0, s1;
#pragma unroll
                for (int i = 0; i < 16; ++i) { s0[i] = 0.f; s1[i] = 0.f; }
                __builtin_amdgcn_s_setprio(1);
#pragma unroll
                for (int m = 0; m < 8; m += 2) {
                    s0 = __builtin_amdgcn_mfma_f32_32x32x16_f16(kf[m],     qf[m],     s0, 0, 0, 0);
                    s1 = __builtin_amdgcn_mfma_f32_32x32x16_f16(kf[m + 1], qf[m + 1], s1, 0, 0, 0);
                }
                __builtin_amdgcn_s_setprio(0);

                f32x16 sv = s0 + s1;

                // --- causal mask (diagonal tile only)
                if (kv0 == q0w) {
#pragma unroll
                    for (int i = 0; i < 16; ++i) {
                        const int krel = (i & 3) + 8 * (i >> 2) + 4 * hi;
                        if (kv0 + krel > q_abs) sv[i] = -1e30f;
                    }
                }

                // --- in-register online softmax (per-lane = one q-row), exp2
                float t0 = fmaxf(sv[0], sv[1]),  t1 = fmaxf(sv[2], sv[3]);
                float t2 = fmaxf(sv[4], sv[5]),  t3 = fmaxf(sv[6], sv[7]);
                float t4 = fmaxf(sv[8], sv[9]),  t5 = fmaxf(sv[10], sv[11]);
                float t6 = fmaxf(sv[12], sv[13]), t7 = fmaxf(sv[14], sv[15]);
                t0 = fmaxf(t0, t1); t2 = fmaxf(t2, t3);
                t4 = fmaxf(t4, t5); t6 = fmaxf(t6, t7);
                float tm = fmaxf(fmaxf(t0, t2), fmaxf(t4, t6));
                tm = fmaxf(tm, __shfl_xor(tm, 32, 64));

                // defer-max (T13): rescale only when max grew by > 8
                if (!__all(tm - m_run <= 8.0f)) {
                    const float mnew = fmaxf(m_run, tm);
                    const float corr = exp2f(m_run - mnew);
                    l_run *= corr;
#pragma unroll
                    for (int e = 0; e < 4; ++e)
#pragma unroll
                        for (int i = 0; i < 16; ++i) acc[e][i] *= corr;
                    m_run = mnew;
                }

#pragma unroll
                for (int i = 0; i < 16; ++i) sv[i] = exp2f(sv[i] - m_run);
                float r0 = (sv[0] + sv[1]) + (sv[2] + sv[3]);
                float r1 = (sv[4] + sv[5]) + (sv[6] + sv[7]);
                float r2 = (sv[8] + sv[9]) + (sv[10] + sv[11]);
                float r3 = (sv[12] + sv[13]) + (sv[14] + sv[15]);
                float rs = (r0 + r1) + (r2 + r3);

                // --- P^T pack + cross-half redistribution
                unsigned u0 = __builtin_bit_cast(unsigned, __builtin_amdgcn_cvt_pkrtz(sv[0],  sv[1]));
                unsigned u1 = __builtin_bit_cast(unsigned, __builtin_amdgcn_cvt_pkrtz(sv[2],  sv[3]));
                unsigned u2 = __builtin_bit_cast(unsigned, __builtin_amdgcn_cvt_pkrtz(sv[4],  sv[5]));
                unsigned u3 = __builtin_bit_cast(unsigned, __builtin_amdgcn_cvt_pkrtz(sv[6],  sv[7]));
                unsigned u4 = __builtin_bit_cast(unsigned, __builtin_amdgcn_cvt_pkrtz(sv[8],  sv[9]));
                unsigned u5 = __builtin_bit_cast(unsigned, __builtin_amdgcn_cvt_pkrtz(sv[10], sv[11]));
                unsigned u6 = __builtin_bit_cast(unsigned, __builtin_amdgcn_cvt_pkrtz(sv[12], sv[13]));
                unsigned u7 = __builtin_bit_cast(unsigned, __builtin_amdgcn_cvt_pkrtz(sv[14], sv[15]));
                permswap(u0, u2); permswap(u1, u3);
                permswap(u4, u6); permswap(u5, u7);
                union uf8 { unsigned w[4]; f16x8 v; };
                uf8 p0; p0.w[0] = u0; p0.w[1] = u1; p0.w[2] = u2; p0.w[3] = u3;
                uf8 p1; p1.w[0] = u4; p1.w[1] = u5; p1.w[2] = u6; p1.w[3] = u7;

                // --- O^T += V^T · P^T
                __builtin_amdgcn_s_setprio(1);
#pragma unroll
                for (int e = 0; e < 4; ++e) {
                    acc[e] = __builtin_amdgcn_mfma_f32_32x32x16_f16(vf[2 * e],     p0.v, acc[e], 0, 0, 0);
                    acc[e] = __builtin_amdgcn_mfma_f32_32x32x16_f16(vf[2 * e + 1], p1.v, acc[e], 0, 0, 0);
                }
                __builtin_amdgcn_s_setprio(0);

                // --- cross-half sum overlaps the MFMA pipe
                rs += __shfl_xor(rs, 32, 64);
                l_run += rs;
            }
        }

        // --- 4-way KV-split combine (R8-verified pattern): roles 1-3 write
        //     partial (m,l,O); role 0 merges all 4 and stores.
        if (role != 0) {
            if (hi == 0) {
                mlbuf[qsub][role - 1][0][q] = m_run;
                mlbuf[qsub][role - 1][1][q] = l_run;
            }
#pragma unroll
            for (int e = 0; e < 4; ++e)
#pragma unroll
                for (int i = 0; i < 16; ++i) {
                    const int erow = e * 32 + (i & 3) + 8 * (i >> 2) + 4 * hi;
                    obuf[qsub][role - 1][q][erow] = (_Float16)acc[e][i];
                }
        }
        __syncthreads();
        if (role == 0) {
            const float m1 = mlbuf[qsub][0][0][q], l1 = mlbuf[qsub][0][1][q];
            const float m2 = mlbuf[qsub][1][0][q], l2 = mlbuf[qsub][1][1][q];
            const float m3 = mlbuf[qsub][2][0][q], l3 = mlbuf[qsub][2][1][q];
            const float ms = fmaxf(fmaxf(m_run, m1), fmaxf(m2, m3));
            const float c0 = exp2f(m_run - ms);
            const float c1 = exp2f(m1 - ms);
            const float c2 = exp2f(m2 - ms);
            const float c3 = exp2f(m3 - ms);
            const float rinv = 1.0f / (l_run * c0 + l1 * c1 + l2 * c2 + l3 * c3);
            float* orow = out + (size_t)q_abs * (NHEAD * DHEAD) + h * DHEAD;
#pragma unroll
            for (int e = 0; e < 4; ++e) {
#pragma unroll
                for (int g = 0; g < 4; ++g) {
                    f32x4 vv;
#pragma unroll
                    for (int c = 0; c < 4; ++c) {
                        const int i = g * 4 + c;
                        const int erow = e * 32 + 8 * g + 4 * hi + c;
                        vv[c] = (acc[e][i] * c0
                                 + (float)obuf[qsub][0][q][erow] * c1
                                 + (float)obuf[qsub][1][q][erow] * c2
                                 + (float)obuf[qsub][2][q][erow] * c3) * rinv;
                    }
                    *(f32x4*)(orow + e * 32 + 8 * g + 4 * hi) = vv;
                }
            }
        }
        // merge reads must finish before next phase's staging overwrites state
        __syncthreads();
    }
}

// ---------------------------------------------------------------------------
extern "C" void kernel_launch(void* const* d_in, const int* in_sizes, int n_in,
                              void* d_out, int out_size, void* d_ws, size_t ws_size,
                              hipStream_t stream) {
    const float* q_in = (const float*)d_in[0];
    const float* k_in = (const float*)d_in[1];
    const float* v_in = (const float*)d_in[2];
    // d_in[3] = attention_mask (strict causal triu) -- implemented analytically
    const float* w_qk = (const float*)d_in[4];
    const float* w_v  = (const float*)d_in[5];
    float* out = (float*)d_out;

    const size_t mat_elems = (size_t)NHEAD * S_LEN * DHEAD;
    const size_t w_elems   = (size_t)NHEAD * DHEAD * DHEAD;
    _Float16* Qp   = (_Float16*)d_ws;
    _Float16* Kp   = Qp + mat_elems;
    _Float16* Vt   = Kp + mat_elems;
    _Float16* Wqkt = Vt + mat_elems;
    _Float16* Wvt  = Wqkt + w_elems;

    transpose_w_kernel<<<dim3(16, NHEAD, 2), dim3(256), 0, stream>>>(w_qk, w_v, Wqkt, Wvt);
    proj_kernel<<<dim3(NHEAD * 32), dim3(512), 0, stream>>>(q_in, k_in, v_in, Wqkt, Wvt, Qp, Kp, Vt);
    attn_kernel<<<dim3(16, NHEAD), dim3(512), 0, stream>>>(Qp, Kp, Vt, out);
}